// Round 1
// baseline (89.645 us; speedup 1.0000x reference)
//
#include <hip/hip_runtime.h>

#define B   64
#define C   128
#define H   56
#define HW  3136      // 56*56
#define HW4 784       // HW/4

// ---------------- Kernel 1: channel-partial sums -----------------
// grid = B * nchunk blocks, 256 threads. Each block sums `cpc` channels of one
// batch's feature map into part[chunk][b][3136]. float4 loads (16B/lane).
__global__ __launch_bounds__(256) void chansum_kernel(const float4* __restrict__ fm,
                                                      float4* __restrict__ part,
                                                      int nchunk, int cpc) {
    int b     = blockIdx.x / nchunk;
    int chunk = blockIdx.x - b * nchunk;
    const float4* base = fm + ((size_t)b * C + (size_t)chunk * cpc) * HW4;
    float4* dst = part + ((size_t)chunk * B + b) * HW4;
    for (int i = threadIdx.x; i < HW4; i += 256) {
        float4 acc = {0.f, 0.f, 0.f, 0.f};
        for (int c = 0; c < cpc; ++c) {
            float4 v = base[(size_t)c * HW4 + i];
            acc.x += v.x; acc.y += v.y; acc.z += v.z; acc.w += v.w;
        }
        dst[i] = acc;
    }
}

// ---------------- Kernel 2: pooled map + 3 peaks + boxes ----------------
// grid = 2*B blocks: b = blockIdx & 63, type = blockIdx >> 6.
__global__ __launch_bounds__(256) void peaks_kernel(const float* __restrict__ part,
                                                    int nchunk,
                                                    const int* __restrict__ scale,
                                                    float* __restrict__ out) {
    const int b    = blockIdx.x & 63;
    const int type = blockIdx.x >> 6;
    const int k    = (type == 0) ? 3 : 2;
    const int Hs   = H - k + 1;            // 54 or 55
    const int n    = Hs * Hs;              // 2916 or 3025
    const int half = (type == 0) ? 112 : 56;  // PATCH_SIZE/2 (even sizes)

    __shared__ float S[HW];
    __shared__ float A[3025];
    __shared__ float rv[256];
    __shared__ int   ri[256];

    const int tid = threadIdx.x;

    // reduce channel-chunk partials into S
    for (int i = tid; i < HW; i += 256) {
        float acc = 0.f;
        for (int ch = 0; ch < nchunk; ++ch)
            acc += part[((size_t)ch * B + b) * HW + i];
        S[i] = acc;
    }
    __syncthreads();

    // pooled score map: window sum / k^2 (true division to match reference)
    const float kk = (float)(k * k);
    for (int i = tid; i < n; i += 256) {
        int r = i / Hs, c = i - r * Hs;
        float sum = 0.f;
        for (int dr = 0; dr < k; ++dr)
            for (int dc = 0; dc < k; ++dc)
                sum += S[(r + dr) * H + (c + dc)];
        A[i] = sum / kk;
    }
    __syncthreads();

    for (int p = 0; p < 3; ++p) {
        // per-thread argmax (ascending index + strict '>' keeps first occurrence)
        float bv = -3.4e38f; int bi = 0x7fffffff;
        for (int i = tid; i < n; i += 256) {
            float v = A[i];
            if (v > bv) { bv = v; bi = i; }
        }
        rv[tid] = bv; ri[tid] = bi;
        __syncthreads();
        // tree reduce, tie-break on smaller index (jnp.argmax first-occurrence)
        for (int s = 128; s > 0; s >>= 1) {
            if (tid < s) {
                float v2 = rv[tid + s]; int i2 = ri[tid + s];
                if (v2 > rv[tid] || (v2 == rv[tid] && i2 < ri[tid])) {
                    rv[tid] = v2; ri[tid] = i2;
                }
            }
            __syncthreads();
        }
        const float vmax = rv[0];
        const int   idx  = ri[0];

        // exact reference erase: zero p iff clipped 3x3 neighborhood holds vmax
        unsigned zmask = 0u;
        {
            int j = 0;
            for (int i = tid; i < n; i += 256, ++j) {
                int r = i / Hs, c = i - r * Hs;
                bool hit = false;
                for (int dr = -1; dr <= 1; ++dr) {
                    int rr = r + dr; if (rr < 0 || rr >= Hs) continue;
                    for (int dc = -1; dc <= 1; ++dc) {
                        int cc = c + dc; if (cc < 0 || cc >= Hs) continue;
                        hit |= (A[rr * Hs + cc] == vmax);
                    }
                }
                if (hit) zmask |= (1u << j);
            }
        }
        __syncthreads();
        {
            int j = 0;
            for (int i = tid; i < n; i += 256, ++j)
                if (zmask & (1u << j)) A[i] = 0.0f;
        }

        if (tid == 0) {
            int lr = idx / Hs, lc = idx - (idx / Hs) * Hs;
            int pg = type * 3 + p;                  // global peak index 0..5
            // fps_loc at offset 1536, values at 2304 (float-encoded ints)
            out[1536 + (b * 6 + pg) * 2 + 0] = (float)lr;
            out[1536 + (b * 6 + pg) * 2 + 1] = (float)lc;
            out[2304 + b * 6 + pg] = vmax;

            int s0 = scale[b * 2 + 0], s1 = scale[b * 2 + 1];
            int smin = s0 < s1 ? s0 : s1;
            int sb0 = (s0 - smin) >> 1, sb1 = (s1 - smin) >> 1;
            // rate = (2*l + H - Hs + 1) / (2H); avoid FMA contraction to match numpy
            float rate_h = (float)(2 * lr + H - Hs + 1) / (2.0f * H);
            float rate_w = (float)(2 * lc + H - Hs + 1) / (2.0f * H);
            int c0 = (int)__fadd_rn((float)sb0, __fmul_rn((float)smin, rate_h));
            int c1 = (int)__fadd_rn((float)sb1, __fmul_rn((float)smin, rate_w));
            int top = c0 - half, bot = c0 + half;
            int lef = c1 - half, rig = c1 + half;
            int bel0 = top < 0 ? top : 0, bel1 = lef < 0 ? lef : 0;
            top -= bel0; bot -= bel0; lef -= bel1; rig -= bel1;
            int ov0 = (bot - s0 > 0) ? (bot - s0) : 0;
            int ov1 = (rig - s1 > 0) ? (rig - s1) : 0;
            top = (top - ov0 > 0) ? (top - ov0) : 0;
            lef = (lef - ov1 > 0) ? (lef - ov1) : 0;
            bot -= ov0; rig -= ov1;
            float* il = out + (size_t)(b * 6 + pg) * 4;
            il[0] = (float)top; il[1] = (float)lef;
            il[2] = (float)bot; il[3] = (float)rig;
        }
        __syncthreads();   // A-zeroing & output visible before next round's scan
    }
}

extern "C" void kernel_launch(void* const* d_in, const int* in_sizes, int n_in,
                              void* d_out, int out_size, void* d_ws, size_t ws_size,
                              hipStream_t stream) {
    const float* fm    = (const float*)d_in[0];
    const int*   scale = (const int*)d_in[1];
    float*       out   = (float*)d_out;

    // channel-chunk count: 8 if workspace allows (6.4 MB), else shrink (pow2)
    const size_t per_chunk = (size_t)B * HW * sizeof(float);   // 802816 B
    int nchunk = 8;
    while (nchunk > 1 && (size_t)nchunk * per_chunk > ws_size) nchunk >>= 1;
    int cpc = C / nchunk;
    float* part = (float*)d_ws;

    hipLaunchKernelGGL(chansum_kernel, dim3(B * nchunk), dim3(256), 0, stream,
                       (const float4*)fm, (float4*)part, nchunk, cpc);
    hipLaunchKernelGGL(peaks_kernel, dim3(2 * B), dim3(256), 0, stream,
                       part, nchunk, scale, out);
}

// Round 2
// 47.199 us; speedup vs baseline: 1.8993x; 1.8993x over previous
//
#include <hip/hip_runtime.h>

#define B   64
#define C   128
#define H   56
#define HW  3136      // 56*56
#define HW4 784       // HW/4
#define NEG_INF (-3.402823466e38f)

// ---------------- Kernel 1: channel-partial sums -----------------
// grid = B * nchunk (1024 at nchunk=16), 256 threads. Each block sums cpc
// channels of one batch into part[b][chunk][3136]. float4 loads.
__global__ __launch_bounds__(256) void chansum_kernel(const float4* __restrict__ fm,
                                                      float4* __restrict__ part,
                                                      int nchunk, int cpc) {
    int b     = blockIdx.x / nchunk;
    int chunk = blockIdx.x - b * nchunk;
    const float4* base = fm + ((size_t)b * C + (size_t)chunk * cpc) * HW4;
    float4* dst = part + ((size_t)b * nchunk + chunk) * HW4;
    for (int i = threadIdx.x; i < HW4; i += 256) {
        float x = 0.f, y = 0.f, z = 0.f, w = 0.f;
        for (int c = 0; c < cpc; ++c) {
            float4 v = base[(size_t)c * HW4 + i];
            x += v.x; y += v.y; z += v.z; w += v.w;
        }
        dst[i] = make_float4(x, y, z, w);
    }
}

// ---------------- Kernel 2: pooled map + 3 peaks + boxes ----------------
struct SharedMem {
    float S[HW];         // channel-summed 56x56 map
    float rv[4];         // per-wave argmax value
    int   ri[4];         // per-wave argmax index
    int   hcnt[3];       // per-round hit count
    int   hlist[3][64];  // per-round hit indices (cells == vmax)
};

template<int TYPE>
__device__ void peaks_body(SharedMem& sm, const float4* __restrict__ part,
                           int nchunk, const int* __restrict__ scale,
                           float* __restrict__ out, int b) {
    constexpr int K    = (TYPE == 0) ? 3 : 2;
    constexpr int Hs   = H - K + 1;          // 54 / 55
    constexpr int n    = Hs * Hs;            // 2916 / 3025
    constexpr int half = (TYPE == 0) ? 112 : 56;
    constexpr int NJ   = 12;                 // ceil(n/256)

    const int tid  = threadIdx.x;
    const int lane = tid & 63;
    const int wave = tid >> 6;

    // Phase 1: S = sum of channel-chunk partials (float4, coalesced)
    {
        float4* S4 = reinterpret_cast<float4*>(sm.S);
        const float4* pb = part + (size_t)b * nchunk * HW4;
        for (int i = tid; i < HW4; i += 256) {
            float x = 0.f, y = 0.f, z = 0.f, w = 0.f;
            for (int ch = 0; ch < nchunk; ++ch) {
                float4 v = pb[ch * HW4 + i];
                x += v.x; y += v.y; z += v.z; w += v.w;
            }
            S4[i] = make_float4(x, y, z, w);
        }
        if (tid == 0) { sm.hcnt[0] = 0; sm.hcnt[1] = 0; sm.hcnt[2] = 0; }
    }
    __syncthreads();

    // Phase 2: pooled score map cached in registers (12 values/thread)
    float av[NJ];
    #pragma unroll
    for (int j = 0; j < NJ; ++j) {
        int i = tid + 256 * j;
        if (i < n) {
            int r = i / Hs, c = i - (i / Hs) * Hs;   // constexpr Hs -> magic mul
            float s = 0.f;
            #pragma unroll
            for (int dr = 0; dr < K; ++dr)
                #pragma unroll
                for (int dc = 0; dc < K; ++dc)
                    s += sm.S[(r + dr) * H + (c + dc)];
            av[j] = s / (float)(K * K);
        } else {
            av[j] = NEG_INF;
        }
    }

    for (int p = 0; p < 3; ++p) {
        // local argmax over cached regs (strict '>' keeps smallest index)
        float bv = NEG_INF; int bi = 0x7fffffff;
        #pragma unroll
        for (int j = 0; j < NJ; ++j)
            if (av[j] > bv) { bv = av[j]; bi = tid + 256 * j; }
        // 64-lane butterfly, tie-break min index (first occurrence)
        #pragma unroll
        for (int d = 1; d < 64; d <<= 1) {
            float ov = __shfl_xor(bv, d);
            int   oi = __shfl_xor(bi, d);
            if (ov > bv || (ov == bv && oi < bi)) { bv = ov; bi = oi; }
        }
        if (lane == 0) { sm.rv[wave] = bv; sm.ri[wave] = bi; }
        __syncthreads();                               // B1: rv/ri visible
        float vmax = sm.rv[0]; int idx = sm.ri[0];
        #pragma unroll
        for (int w = 1; w < 4; ++w) {
            float ov = sm.rv[w]; int oi = sm.ri[w];
            if (ov > vmax || (ov == vmax && oi < idx)) { vmax = ov; idx = oi; }
        }

        if (tid == 0) {
            int lr = idx / Hs, lc = idx - (idx / Hs) * Hs;
            int pg = TYPE * 3 + p;
            out[1536 + (b * 6 + pg) * 2 + 0] = (float)lr;
            out[1536 + (b * 6 + pg) * 2 + 1] = (float)lc;
            out[2304 + b * 6 + pg] = vmax;

            int s0 = scale[b * 2 + 0], s1 = scale[b * 2 + 1];
            int smin = s0 < s1 ? s0 : s1;
            int sb0 = (s0 - smin) >> 1, sb1 = (s1 - smin) >> 1;
            float rate_h = (float)(2 * lr + H - Hs + 1) / (2.0f * H);
            float rate_w = (float)(2 * lc + H - Hs + 1) / (2.0f * H);
            int c0 = (int)__fadd_rn((float)sb0, __fmul_rn((float)smin, rate_h));
            int c1 = (int)__fadd_rn((float)sb1, __fmul_rn((float)smin, rate_w));
            int top = c0 - half, bot = c0 + half;
            int lef = c1 - half, rig = c1 + half;
            int bel0 = top < 0 ? top : 0, bel1 = lef < 0 ? lef : 0;
            top -= bel0; bot -= bel0; lef -= bel1; rig -= bel1;
            int ov0 = (bot - s0 > 0) ? (bot - s0) : 0;
            int ov1 = (rig - s1 > 0) ? (rig - s1) : 0;
            top = (top - ov0 > 0) ? (top - ov0) : 0;
            lef = (lef - ov1 > 0) ? (lef - ov1) : 0;
            bot -= ov0; rig -= ov1;
            float* il = out + (size_t)(b * 6 + pg) * 4;
            il[0] = (float)top; il[1] = (float)lef;
            il[2] = (float)bot; il[3] = (float)rig;
        }

        // exact reference erase: every cell == vmax gets its 3x3 box zeroed.
        // hits detected from this round's cached (pre-erase) values.
        #pragma unroll
        for (int j = 0; j < NJ; ++j) {
            if (av[j] == vmax) {
                int pos = atomicAdd(&sm.hcnt[p], 1);
                if (pos < 64) sm.hlist[p][pos] = tid + 256 * j;
            }
        }
        __syncthreads();                               // B2: hits visible
        if (p < 2) {
            int cnt = sm.hcnt[p]; if (cnt > 64) cnt = 64;
            for (int h = 0; h < cnt; ++h) {
                int hi = sm.hlist[p][h];
                int hr = hi / Hs, hc = hi - (hi / Hs) * Hs;
                #pragma unroll
                for (int j = 0; j < NJ; ++j) {
                    int i = tid + 256 * j;
                    int r = i / Hs, c = i - (i / Hs) * Hs;
                    bool inbox = (i < n) & (r >= hr - 1) & (r <= hr + 1)
                                         & (c >= hc - 1) & (c <= hc + 1);
                    if (inbox) av[j] = 0.f;
                }
            }
        }
        // no third barrier: rv/ri writes of round p+1 occur after B2, and all
        // rv/ri reads of round p happened before B2.
    }
}

__global__ __launch_bounds__(256) void peaks_kernel(const float4* __restrict__ part,
                                                    int nchunk,
                                                    const int* __restrict__ scale,
                                                    float* __restrict__ out) {
    __shared__ SharedMem sm;
    int bb = blockIdx.x;
    int b  = bb & 63;
    if (bb < 64) peaks_body<0>(sm, part, nchunk, scale, out, b);
    else         peaks_body<1>(sm, part, nchunk, scale, out, b);
}

extern "C" void kernel_launch(void* const* d_in, const int* in_sizes, int n_in,
                              void* d_out, int out_size, void* d_ws, size_t ws_size,
                              hipStream_t stream) {
    const float* fm    = (const float*)d_in[0];
    const int*   scale = (const int*)d_in[1];
    float*       out   = (float*)d_out;

    const size_t per_chunk = (size_t)B * HW * sizeof(float);   // 802816 B
    int nchunk = 16;                                           // 12.85 MB at 16
    while (nchunk > 1 && (size_t)nchunk * per_chunk > ws_size) nchunk >>= 1;
    int cpc = C / nchunk;
    float* part = (float*)d_ws;

    hipLaunchKernelGGL(chansum_kernel, dim3(B * nchunk), dim3(256), 0, stream,
                       (const float4*)fm, (float4*)part, nchunk, cpc);
    hipLaunchKernelGGL(peaks_kernel, dim3(2 * B), dim3(256), 0, stream,
                       (const float4*)part, nchunk, scale, out);
}